// Round 3
// baseline (1545.571 us; speedup 1.0000x reference)
//
#include <hip/hip_runtime.h>
#include <hip/hip_bf16.h>

#define BB    8
#define NNTOK 1024
#define CCH   640
#define HH    8
#define DHD   80
#define RRW   3
#define MM    (BB * NNTOK)      // 8192
#define INNER 640
#define SCALE 0.111803398874989484820458954f  // 80^-0.5

// Y[m][i] = sum_c X[m][c] * W[i][c]; X, W f32 row-major over c; Y f32.
// Tile 64x64, BK=32, 256 threads, 4x4 micro-tile. blockIdx.z selects Wq/Wk/Wv.
__global__ __launch_bounds__(256) void qkv_proj_kernel(
    const float* __restrict__ x,
    const float* __restrict__ wq, const float* __restrict__ wk, const float* __restrict__ wv,
    float* __restrict__ qb, float* __restrict__ kb, float* __restrict__ vb)
{
    __shared__ float Xs[32 * 68];   // [k][m] stride 68 (16B-aligned rows, conflict-spread)
    __shared__ float Ws[32 * 68];   // [k][i]
    const int t = threadIdx.x;
    const int m0 = blockIdx.x * 64;
    const int i0 = blockIdx.y * 64;
    const float* W = (blockIdx.z == 0) ? wq : (blockIdx.z == 1) ? wk : wv;
    float* Y = (blockIdx.z == 0) ? qb : (blockIdx.z == 1) ? kb : vb;

    const int row = t >> 2;   // 0..63
    const int seg = t & 3;    // 0..3 (8 floats each)
    const int ty = t >> 4;    // 0..15 -> rows ty*4..+3
    const int tx = t & 15;    // 0..15 -> cols tx*4..+3

    float acc[4][4] = {};

    for (int kt = 0; kt < CCH; kt += 32) {
        float4 x0 = *(const float4*)(x + (size_t)(m0 + row) * CCH + kt + seg * 8);
        float4 x1 = *(const float4*)(x + (size_t)(m0 + row) * CCH + kt + seg * 8 + 4);
        float4 w0 = *(const float4*)(W + (size_t)(i0 + row) * CCH + kt + seg * 8);
        float4 w1 = *(const float4*)(W + (size_t)(i0 + row) * CCH + kt + seg * 8 + 4);
        __syncthreads();
        Xs[(seg * 8 + 0) * 68 + row] = x0.x;
        Xs[(seg * 8 + 1) * 68 + row] = x0.y;
        Xs[(seg * 8 + 2) * 68 + row] = x0.z;
        Xs[(seg * 8 + 3) * 68 + row] = x0.w;
        Xs[(seg * 8 + 4) * 68 + row] = x1.x;
        Xs[(seg * 8 + 5) * 68 + row] = x1.y;
        Xs[(seg * 8 + 6) * 68 + row] = x1.z;
        Xs[(seg * 8 + 7) * 68 + row] = x1.w;
        Ws[(seg * 8 + 0) * 68 + row] = w0.x;
        Ws[(seg * 8 + 1) * 68 + row] = w0.y;
        Ws[(seg * 8 + 2) * 68 + row] = w0.z;
        Ws[(seg * 8 + 3) * 68 + row] = w0.w;
        Ws[(seg * 8 + 4) * 68 + row] = w1.x;
        Ws[(seg * 8 + 5) * 68 + row] = w1.y;
        Ws[(seg * 8 + 6) * 68 + row] = w1.z;
        Ws[(seg * 8 + 7) * 68 + row] = w1.w;
        __syncthreads();
#pragma unroll
        for (int kk = 0; kk < 32; kk++) {
            float4 a = *(const float4*)&Xs[kk * 68 + ty * 4];
            float4 b = *(const float4*)&Ws[kk * 68 + tx * 4];
            acc[0][0] += a.x * b.x; acc[0][1] += a.x * b.y; acc[0][2] += a.x * b.z; acc[0][3] += a.x * b.w;
            acc[1][0] += a.y * b.x; acc[1][1] += a.y * b.y; acc[1][2] += a.y * b.z; acc[1][3] += a.y * b.w;
            acc[2][0] += a.z * b.x; acc[2][1] += a.z * b.y; acc[2][2] += a.z * b.z; acc[2][3] += a.z * b.w;
            acc[3][0] += a.w * b.x; acc[3][1] += a.w * b.y; acc[3][2] += a.w * b.z; acc[3][3] += a.w * b.w;
        }
    }
#pragma unroll
    for (int jr = 0; jr < 4; jr++) {
        float4 o = make_float4(acc[jr][0], acc[jr][1], acc[jr][2], acc[jr][3]);
        *(float4*)&Y[(size_t)(m0 + ty * 4 + jr) * INNER + i0 + tx * 4] = o;
    }
}

// Flash-style windowed attention. One block per (qtile of 64, head, batch-frame).
// K-chunks of 64 keys; K and V share one LDS buffer (K transposed [k][n], V natural [n][k]).
__global__ __launch_bounds__(256) void attn_kernel(
    const float* __restrict__ qb, const float* __restrict__ kb, const float* __restrict__ vb,
    const int* __restrict__ ctx, float* __restrict__ ob)
{
    __shared__ float Qs[DHD * 64];   // [k][m]
    __shared__ float KVs[DHD * 64];  // phase 1: K as [k][n]; phase 2: V as [n][k]
    __shared__ float Ss[64 * 65];    // S then P
    __shared__ float mrow[64], lrow[64], arow[64];

    const int t = threadIdx.x;
    const int qt = blockIdx.x, h = blockIdx.y, b = blockIdx.z;
    const int n0 = qt * 64;
    const int row = t >> 2;          // 0..63
    const int c0 = (t & 3) * 20;     // 0,20,40,60
    const int ty = t >> 4, tx = t & 15;

    // Load Q tile transposed into LDS
    {
        const float* qp = qb + (size_t)(b * NNTOK + n0 + row) * INNER + h * DHD + c0;
#pragma unroll
        for (int v5 = 0; v5 < 5; v5++) {
            float4 f = *(const float4*)(qp + v5 * 4);
            Qs[(c0 + v5 * 4 + 0) * 64 + row] = f.x;
            Qs[(c0 + v5 * 4 + 1) * 64 + row] = f.y;
            Qs[(c0 + v5 * 4 + 2) * 64 + row] = f.z;
            Qs[(c0 + v5 * 4 + 3) * 64 + row] = f.w;
        }
    }
    if (t < 64) { mrow[t] = -1e30f; lrow[t] = 0.0f; }

    float o[20];
#pragma unroll
    for (int i = 0; i < 20; i++) o[i] = 0.0f;

    for (int kc = 0; kc < (RRW * NNTOK) / 64; kc++) {   // 48 chunks
        const int w0 = kc * 64;
        const int fr = ctx[b * RRW + (w0 >> 10)];
        const int tok0 = w0 & (NNTOK - 1);
        const size_t src = (size_t)(fr * NNTOK + tok0 + row) * INNER + h * DHD + c0;

        __syncthreads();   // previous PV (reads KVs as V, Ss) done
        // load K chunk transposed
#pragma unroll
        for (int v5 = 0; v5 < 5; v5++) {
            float4 f = *(const float4*)(kb + src + v5 * 4);
            KVs[(c0 + v5 * 4 + 0) * 64 + row] = f.x;
            KVs[(c0 + v5 * 4 + 1) * 64 + row] = f.y;
            KVs[(c0 + v5 * 4 + 2) * 64 + row] = f.z;
            KVs[(c0 + v5 * 4 + 3) * 64 + row] = f.w;
        }
        __syncthreads();
        // S = scale * Q K^T  (4x4 per thread)
        {
            float s[4][4] = {};
            for (int kk = 0; kk < DHD; kk++) {
                float4 a = *(const float4*)&Qs[kk * 64 + ty * 4];
                float4 k4 = *(const float4*)&KVs[kk * 64 + tx * 4];
                s[0][0] += a.x * k4.x; s[0][1] += a.x * k4.y; s[0][2] += a.x * k4.z; s[0][3] += a.x * k4.w;
                s[1][0] += a.y * k4.x; s[1][1] += a.y * k4.y; s[1][2] += a.y * k4.z; s[1][3] += a.y * k4.w;
                s[2][0] += a.z * k4.x; s[2][1] += a.z * k4.y; s[2][2] += a.z * k4.z; s[2][3] += a.z * k4.w;
                s[3][0] += a.w * k4.x; s[3][1] += a.w * k4.y; s[3][2] += a.w * k4.z; s[3][3] += a.w * k4.w;
            }
#pragma unroll
            for (int jr = 0; jr < 4; jr++)
#pragma unroll
                for (int jc = 0; jc < 4; jc++)
                    Ss[(ty * 4 + jr) * 65 + tx * 4 + jc] = s[jr][jc] * SCALE;
        }
        __syncthreads();   // S visible; all K reads done -> KVs reusable for V
        // load V chunk (natural layout) into same buffer
#pragma unroll
        for (int v5 = 0; v5 < 5; v5++) {
            float4 f = *(const float4*)(vb + src + v5 * 4);
            *(float4*)&KVs[row * DHD + c0 + v5 * 4] = f;
        }
        // online softmax per row (threads 0..63)
        if (t < 64) {
            float* sr = &Ss[t * 65];
            float mo = mrow[t];
            float mx = mo;
            for (int j = 0; j < 64; j++) mx = fmaxf(mx, sr[j]);
            float al = __expf(mo - mx);
            float sum = 0.0f;
            for (int j = 0; j < 64; j++) { float p = __expf(sr[j] - mx); sr[j] = p; sum += p; }
            lrow[t] = lrow[t] * al + sum;
            mrow[t] = mx;
            arow[t] = al;
        }
        __syncthreads();
        // O = O*alpha + P V
        {
            float al = arow[row];
#pragma unroll
            for (int i = 0; i < 20; i++) o[i] *= al;
            for (int j = 0; j < 64; j++) {
                float p = Ss[row * 65 + j];
#pragma unroll
                for (int v5 = 0; v5 < 5; v5++) {
                    float4 vv = *(const float4*)&KVs[j * DHD + c0 + v5 * 4];
                    o[v5 * 4 + 0] += p * vv.x;
                    o[v5 * 4 + 1] += p * vv.y;
                    o[v5 * 4 + 2] += p * vv.z;
                    o[v5 * 4 + 3] += p * vv.w;
                }
            }
        }
    }
    const float inv = 1.0f / lrow[row];
    float* op = ob + (size_t)(b * NNTOK + n0 + row) * INNER + h * DHD + c0;
#pragma unroll
    for (int v5 = 0; v5 < 5; v5++) {
        float4 f = make_float4(o[v5 * 4 + 0] * inv, o[v5 * 4 + 1] * inv,
                               o[v5 * 4 + 2] * inv, o[v5 * 4 + 3] * inv);
        *(float4*)(op + v5 * 4) = f;
    }
}

// out[m][c] = bo[c] + sum_i A[m][i] * Wo[c][i]; A f32 (ws), Wo f32, out f32
__global__ __launch_bounds__(256) void out_proj_kernel(
    const float* __restrict__ A, const float* __restrict__ Wo,
    const float* __restrict__ bo, float* __restrict__ out)
{
    __shared__ float As[32 * 68];
    __shared__ float Ws[32 * 68];
    const int t = threadIdx.x;
    const int m0 = blockIdx.x * 64;
    const int c0b = blockIdx.y * 64;
    const int row = t >> 2;
    const int seg = t & 3;
    const int ty = t >> 4, tx = t & 15;

    float acc[4][4] = {};

    for (int kt = 0; kt < INNER; kt += 32) {
        float4 a0 = *(const float4*)(A + (size_t)(m0 + row) * INNER + kt + seg * 8);
        float4 a1 = *(const float4*)(A + (size_t)(m0 + row) * INNER + kt + seg * 8 + 4);
        float4 w0 = *(const float4*)(Wo + (size_t)(c0b + row) * INNER + kt + seg * 8);
        float4 w1 = *(const float4*)(Wo + (size_t)(c0b + row) * INNER + kt + seg * 8 + 4);
        __syncthreads();
        As[(seg * 8 + 0) * 68 + row] = a0.x;
        As[(seg * 8 + 1) * 68 + row] = a0.y;
        As[(seg * 8 + 2) * 68 + row] = a0.z;
        As[(seg * 8 + 3) * 68 + row] = a0.w;
        As[(seg * 8 + 4) * 68 + row] = a1.x;
        As[(seg * 8 + 5) * 68 + row] = a1.y;
        As[(seg * 8 + 6) * 68 + row] = a1.z;
        As[(seg * 8 + 7) * 68 + row] = a1.w;
        Ws[(seg * 8 + 0) * 68 + row] = w0.x;
        Ws[(seg * 8 + 1) * 68 + row] = w0.y;
        Ws[(seg * 8 + 2) * 68 + row] = w0.z;
        Ws[(seg * 8 + 3) * 68 + row] = w0.w;
        Ws[(seg * 8 + 4) * 68 + row] = w1.x;
        Ws[(seg * 8 + 5) * 68 + row] = w1.y;
        Ws[(seg * 8 + 6) * 68 + row] = w1.z;
        Ws[(seg * 8 + 7) * 68 + row] = w1.w;
        __syncthreads();
#pragma unroll
        for (int kk = 0; kk < 32; kk++) {
            float4 a = *(const float4*)&As[kk * 68 + ty * 4];
            float4 b = *(const float4*)&Ws[kk * 68 + tx * 4];
            acc[0][0] += a.x * b.x; acc[0][1] += a.x * b.y; acc[0][2] += a.x * b.z; acc[0][3] += a.x * b.w;
            acc[1][0] += a.y * b.x; acc[1][1] += a.y * b.y; acc[1][2] += a.y * b.z; acc[1][3] += a.y * b.w;
            acc[2][0] += a.z * b.x; acc[2][1] += a.z * b.y; acc[2][2] += a.z * b.z; acc[2][3] += a.z * b.w;
            acc[3][0] += a.w * b.x; acc[3][1] += a.w * b.y; acc[3][2] += a.w * b.z; acc[3][3] += a.w * b.w;
        }
    }
#pragma unroll
    for (int jr = 0; jr < 4; jr++) {
        const int m = m0 + ty * 4 + jr;
        float4 o = make_float4(acc[jr][0] + bo[c0b + tx * 4 + 0],
                               acc[jr][1] + bo[c0b + tx * 4 + 1],
                               acc[jr][2] + bo[c0b + tx * 4 + 2],
                               acc[jr][3] + bo[c0b + tx * 4 + 3]);
        *(float4*)&out[(size_t)m * CCH + c0b + tx * 4] = o;
    }
}

extern "C" void kernel_launch(void* const* d_in, const int* in_sizes, int n_in,
                              void* d_out, int out_size, void* d_ws, size_t ws_size,
                              hipStream_t stream) {
    const float* x  = (const float*)d_in[0];
    const float* wq = (const float*)d_in[1];
    const float* wk = (const float*)d_in[2];
    const float* wv = (const float*)d_in[3];
    const float* wo = (const float*)d_in[4];
    const float* bo = (const float*)d_in[5];
    const int* ctx  = (const int*)d_in[6];
    float* out = (float*)d_out;

    float* qb = (float*)d_ws;
    float* kb = qb + (size_t)MM * INNER;
    float* vb = kb + (size_t)MM * INNER;
    float* ob = vb + (size_t)MM * INNER;

    qkv_proj_kernel<<<dim3(MM / 64, INNER / 64, 3), 256, 0, stream>>>(x, wq, wk, wv, qb, kb, vb);
    attn_kernel<<<dim3(NNTOK / 64, HH, BB), 256, 0, stream>>>(qb, kb, vb, ctx, ob);
    out_proj_kernel<<<dim3(MM / 64, CCH / 64), 256, 0, stream>>>(ob, wo, bo, out);
}

// Round 6
// 1271.004 us; speedup vs baseline: 1.2160x; 1.2160x over previous
//
#include <hip/hip_runtime.h>
#include <hip/hip_bf16.h>

#define BB    8
#define NNTOK 1024
#define CCH   640
#define HH    8
#define DHD   80
#define RRW   3
#define MM    (BB * NNTOK)      // 8192
#define INNER 640
#define SCALE 0.111803398874989484820458954f  // 80^-0.5

typedef __bf16 bf16x8 __attribute__((ext_vector_type(8)));
typedef float  f32x4  __attribute__((ext_vector_type(4)));

__device__ __forceinline__ unsigned short f2b(float f) {   // f32 -> bf16 bits, RNE
    union { float f; unsigned int u; } v; v.f = f;
    unsigned int r = v.u + 0x7fffu + ((v.u >> 16) & 1u);
    return (unsigned short)(r >> 16);
}
__device__ __forceinline__ f32x4 zero4() {
    f32x4 z;
#pragma unroll
    for (int i = 0; i < 4; i++) z[i] = 0.0f;
    return z;
}

// ---------- f32 -> bf16 cast ----------
__global__ __launch_bounds__(256) void castk(const float* __restrict__ s,
                                             unsigned short* __restrict__ d, int n) {
    int i = (blockIdx.x * 256 + threadIdx.x) * 4;
    if (i < n) {
        float4 f = *(const float4*)(s + i);
        ushort4 o;
        o.x = f2b(f.x); o.y = f2b(f.y); o.z = f2b(f.z); o.w = f2b(f.w);
        *(ushort4*)(d + i) = o;
    }
}

// ---------- QKV projection, bf16 MFMA, f32 row-major outputs ----------
// Y[m][i] = sum_c X[m][c]*W[i][c]. Tile 64x64, BK=64, 4 waves (16 rows x 64 cols each).
__global__ __launch_bounds__(256) void proj_qkv_mfma(
    const unsigned short* __restrict__ xb,
    const unsigned short* __restrict__ wqb,
    const unsigned short* __restrict__ wkb,
    const unsigned short* __restrict__ wvb,
    float* __restrict__ qb, float* __restrict__ kb, float* __restrict__ vb)
{
    __shared__ __align__(16) unsigned short Xs[64 * 72];   // rows padded to 72 bf16 (144B)
    __shared__ __align__(16) unsigned short Wsh[64 * 72];
    const int t = threadIdx.x;
    const int wvid = t >> 6, lane = t & 63, col = lane & 15, quad = lane >> 4;
    const int m0 = blockIdx.x * 64, i0 = blockIdx.y * 64, z = blockIdx.z;
    const unsigned short* W = (z == 0) ? wqb : (z == 1) ? wkb : wvb;
    float* Y = (z == 0) ? qb : (z == 1) ? kb : vb;
    const int row = t >> 2, seg = t & 3;

    f32x4 acc[4];
#pragma unroll
    for (int nt = 0; nt < 4; nt++) acc[nt] = zero4();

    for (int kt = 0; kt < INNER; kt += 64) {
        uint4 x0 = *(const uint4*)(xb + (size_t)(m0 + row) * INNER + kt + seg * 16);
        uint4 x1 = *(const uint4*)(xb + (size_t)(m0 + row) * INNER + kt + seg * 16 + 8);
        uint4 w0 = *(const uint4*)(W  + (size_t)(i0 + row) * INNER + kt + seg * 16);
        uint4 w1 = *(const uint4*)(W  + (size_t)(i0 + row) * INNER + kt + seg * 16 + 8);
        __syncthreads();
        *(uint4*)&Xs[row * 72 + seg * 16]      = x0;
        *(uint4*)&Xs[row * 72 + seg * 16 + 8]  = x1;
        *(uint4*)&Wsh[row * 72 + seg * 16]     = w0;
        *(uint4*)&Wsh[row * 72 + seg * 16 + 8] = w1;
        __syncthreads();
#pragma unroll
        for (int kbk = 0; kbk < 2; kbk++) {
            bf16x8 af = *(const bf16x8*)&Xs[(wvid * 16 + col) * 72 + kbk * 32 + quad * 8];
#pragma unroll
            for (int nt = 0; nt < 4; nt++) {
                bf16x8 bfr = *(const bf16x8*)&Wsh[(nt * 16 + col) * 72 + kbk * 32 + quad * 8];
                acc[nt] = __builtin_amdgcn_mfma_f32_16x16x32_bf16(af, bfr, acc[nt], 0, 0, 0);
            }
        }
    }
#pragma unroll
    for (int nt = 0; nt < 4; nt++)
#pragma unroll
        for (int r = 0; r < 4; r++)
            Y[(size_t)(m0 + wvid * 16 + quad * 4 + r) * INNER + i0 + nt * 16 + col] = acc[nt][r];
}

// ---------- round-3 f32 flash attention (known-PASS), output store -> bf16 ----------
__global__ __launch_bounds__(256) void attn_kernel(
    const float* __restrict__ qb, const float* __restrict__ kb, const float* __restrict__ vb,
    const int* __restrict__ ctx, unsigned short* __restrict__ ao)
{
    __shared__ float Qs[DHD * 64];
    __shared__ float KVs[DHD * 64];
    __shared__ float Ss[64 * 65];
    __shared__ float mrow[64], lrow[64], arow[64];

    const int t = threadIdx.x;
    const int qt = blockIdx.x, h = blockIdx.y, b = blockIdx.z;
    const int n0 = qt * 64;
    const int row = t >> 2;
    const int c0 = (t & 3) * 20;
    const int ty = t >> 4, tx = t & 15;

    {
        const float* qp = qb + (size_t)(b * NNTOK + n0 + row) * INNER + h * DHD + c0;
#pragma unroll
        for (int v5 = 0; v5 < 5; v5++) {
            float4 f = *(const float4*)(qp + v5 * 4);
            Qs[(c0 + v5 * 4 + 0) * 64 + row] = f.x;
            Qs[(c0 + v5 * 4 + 1) * 64 + row] = f.y;
            Qs[(c0 + v5 * 4 + 2) * 64 + row] = f.z;
            Qs[(c0 + v5 * 4 + 3) * 64 + row] = f.w;
        }
    }
    if (t < 64) { mrow[t] = -1e30f; lrow[t] = 0.0f; }

    float o[20];
#pragma unroll
    for (int i = 0; i < 20; i++) o[i] = 0.0f;

    for (int kc = 0; kc < (RRW * NNTOK) / 64; kc++) {
        const int w0 = kc * 64;
        const int fr = ctx[b * RRW + (w0 >> 10)];
        const int tok0 = w0 & (NNTOK - 1);
        const size_t src = (size_t)(fr * NNTOK + tok0 + row) * INNER + h * DHD + c0;

        __syncthreads();
#pragma unroll
        for (int v5 = 0; v5 < 5; v5++) {
            float4 f = *(const float4*)(kb + src + v5 * 4);
            KVs[(c0 + v5 * 4 + 0) * 64 + row] = f.x;
            KVs[(c0 + v5 * 4 + 1) * 64 + row] = f.y;
            KVs[(c0 + v5 * 4 + 2) * 64 + row] = f.z;
            KVs[(c0 + v5 * 4 + 3) * 64 + row] = f.w;
        }
        __syncthreads();
        {
            float s[4][4] = {};
            for (int kk = 0; kk < DHD; kk++) {
                float4 a = *(const float4*)&Qs[kk * 64 + ty * 4];
                float4 k4 = *(const float4*)&KVs[kk * 64 + tx * 4];
                s[0][0] += a.x * k4.x; s[0][1] += a.x * k4.y; s[0][2] += a.x * k4.z; s[0][3] += a.x * k4.w;
                s[1][0] += a.y * k4.x; s[1][1] += a.y * k4.y; s[1][2] += a.y * k4.z; s[1][3] += a.y * k4.w;
                s[2][0] += a.z * k4.x; s[2][1] += a.z * k4.y; s[2][2] += a.z * k4.z; s[2][3] += a.z * k4.w;
                s[3][0] += a.w * k4.x; s[3][1] += a.w * k4.y; s[3][2] += a.w * k4.z; s[3][3] += a.w * k4.w;
            }
#pragma unroll
            for (int jr = 0; jr < 4; jr++)
#pragma unroll
                for (int jc = 0; jc < 4; jc++)
                    Ss[(ty * 4 + jr) * 65 + tx * 4 + jc] = s[jr][jc] * SCALE;
        }
        __syncthreads();
#pragma unroll
        for (int v5 = 0; v5 < 5; v5++) {
            float4 f = *(const float4*)(vb + src + v5 * 4);
            *(float4*)&KVs[row * DHD + c0 + v5 * 4] = f;
        }
        if (t < 64) {
            float* sr = &Ss[t * 65];
            float mo = mrow[t];
            float mx = mo;
            for (int j = 0; j < 64; j++) mx = fmaxf(mx, sr[j]);
            float al = __expf(mo - mx);
            float sum = 0.0f;
            for (int j = 0; j < 64; j++) { float p = __expf(sr[j] - mx); sr[j] = p; sum += p; }
            lrow[t] = lrow[t] * al + sum;
            mrow[t] = mx;
            arow[t] = al;
        }
        __syncthreads();
        {
            float al = arow[row];
#pragma unroll
            for (int i = 0; i < 20; i++) o[i] *= al;
            for (int j = 0; j < 64; j++) {
                float p = Ss[row * 65 + j];
#pragma unroll
                for (int v5 = 0; v5 < 5; v5++) {
                    float4 vv = *(const float4*)&KVs[j * DHD + c0 + v5 * 4];
                    o[v5 * 4 + 0] += p * vv.x;
                    o[v5 * 4 + 1] += p * vv.y;
                    o[v5 * 4 + 2] += p * vv.z;
                    o[v5 * 4 + 3] += p * vv.w;
                }
            }
        }
    }
    const float inv = 1.0f / lrow[row];
    unsigned short* op = ao + (size_t)(b * NNTOK + n0 + row) * INNER + h * DHD + c0;
#pragma unroll
    for (int v5 = 0; v5 < 5; v5++) {
        op[v5 * 4 + 0] = f2b(o[v5 * 4 + 0] * inv);
        op[v5 * 4 + 1] = f2b(o[v5 * 4 + 1] * inv);
        op[v5 * 4 + 2] = f2b(o[v5 * 4 + 2] * inv);
        op[v5 * 4 + 3] = f2b(o[v5 * 4 + 3] * inv);
    }
}

// ---------- out projection, bf16 MFMA, f32 output + bias ----------
__global__ __launch_bounds__(256) void proj_out_mfma(
    const unsigned short* __restrict__ ab, const unsigned short* __restrict__ wob,
    const float* __restrict__ bo, float* __restrict__ out)
{
    __shared__ __align__(16) unsigned short Xs[64 * 72];
    __shared__ __align__(16) unsigned short Wsh[64 * 72];
    const int t = threadIdx.x;
    const int wvid = t >> 6, lane = t & 63, col = lane & 15, quad = lane >> 4;
    const int m0 = blockIdx.x * 64, i0 = blockIdx.y * 64;
    const int row = t >> 2, seg = t & 3;

    float bias[4];
#pragma unroll
    for (int nt = 0; nt < 4; nt++) bias[nt] = bo[i0 + nt * 16 + col];

    f32x4 acc[4];
#pragma unroll
    for (int nt = 0; nt < 4; nt++) acc[nt] = zero4();

    for (int kt = 0; kt < INNER; kt += 64) {
        uint4 x0 = *(const uint4*)(ab  + (size_t)(m0 + row) * INNER + kt + seg * 16);
        uint4 x1 = *(const uint4*)(ab  + (size_t)(m0 + row) * INNER + kt + seg * 16 + 8);
        uint4 w0 = *(const uint4*)(wob + (size_t)(i0 + row) * INNER + kt + seg * 16);
        uint4 w1 = *(const uint4*)(wob + (size_t)(i0 + row) * INNER + kt + seg * 16 + 8);
        __syncthreads();
        *(uint4*)&Xs[row * 72 + seg * 16]      = x0;
        *(uint4*)&Xs[row * 72 + seg * 16 + 8]  = x1;
        *(uint4*)&Wsh[row * 72 + seg * 16]     = w0;
        *(uint4*)&Wsh[row * 72 + seg * 16 + 8] = w1;
        __syncthreads();
#pragma unroll
        for (int kbk = 0; kbk < 2; kbk++) {
            bf16x8 af = *(const bf16x8*)&Xs[(wvid * 16 + col) * 72 + kbk * 32 + quad * 8];
#pragma unroll
            for (int nt = 0; nt < 4; nt++) {
                bf16x8 bfr = *(const bf16x8*)&Wsh[(nt * 16 + col) * 72 + kbk * 32 + quad * 8];
                acc[nt] = __builtin_amdgcn_mfma_f32_16x16x32_bf16(af, bfr, acc[nt], 0, 0, 0);
            }
        }
    }
#pragma unroll
    for (int nt = 0; nt < 4; nt++)
#pragma unroll
        for (int r = 0; r < 4; r++)
            out[(size_t)(m0 + wvid * 16 + quad * 4 + r) * CCH + i0 + nt * 16 + col] = acc[nt][r] + bias[nt];
}

extern "C" void kernel_launch(void* const* d_in, const int* in_sizes, int n_in,
                              void* d_out, int out_size, void* d_ws, size_t ws_size,
                              hipStream_t stream) {
    const float* x  = (const float*)d_in[0];
    const float* wq = (const float*)d_in[1];
    const float* wk = (const float*)d_in[2];
    const float* wv = (const float*)d_in[3];
    const float* wo = (const float*)d_in[4];
    const float* bo = (const float*)d_in[5];
    const int* ctx  = (const int*)d_in[6];
    float* out = (float*)d_out;

    const size_t XN = (size_t)MM * INNER;     // 5,242,880
    const size_t WN = (size_t)INNER * CCH;    //   409,600
    // f32 q/k/v (63 MB), then bf16 region. aob aliases xb (xb dead after proj_qkv,
    // attn writes aob strictly after). Total ~76.7 MB (< 84 MB proven in round 3).
    float* qb = (float*)d_ws;
    float* kb = qb + XN;
    float* vb = kb + XN;
    unsigned short* xb  = (unsigned short*)(vb + XN);
    unsigned short* aob = xb;                 // alias: attention output (bf16)
    unsigned short* wqb = xb + XN;
    unsigned short* wkb = wqb + WN;
    unsigned short* wvb = wkb + WN;
    unsigned short* wob = wvb + WN;

    castk<<<dim3((XN / 4 + 255) / 256), 256, 0, stream>>>(x,  xb,  (int)XN);
    castk<<<dim3((WN / 4 + 255) / 256), 256, 0, stream>>>(wq, wqb, (int)WN);
    castk<<<dim3((WN / 4 + 255) / 256), 256, 0, stream>>>(wk, wkb, (int)WN);
    castk<<<dim3((WN / 4 + 255) / 256), 256, 0, stream>>>(wv, wvb, (int)WN);
    castk<<<dim3((WN / 4 + 255) / 256), 256, 0, stream>>>(wo, wob, (int)WN);

    proj_qkv_mfma<<<dim3(MM / 64, INNER / 64, 3), 256, 0, stream>>>(xb, wqb, wkb, wvb, qb, kb, vb);
    attn_kernel<<<dim3(NNTOK / 64, HH, BB), 256, 0, stream>>>(qb, kb, vb, ctx, aob);
    proj_out_mfma<<<dim3(MM / 64, CCH / 64), 256, 0, stream>>>(aob, wob, bo, out);
}

// Round 7
// 884.749 us; speedup vs baseline: 1.7469x; 1.4366x over previous
//
#include <hip/hip_runtime.h>
#include <hip/hip_bf16.h>

#define BB    8
#define NNTOK 1024
#define CCH   640
#define HH    8
#define DHD   80
#define RRW   3
#define MM    (BB * NNTOK)      // 8192
#define INNER 640
#define SCALE 0.111803398874989484820458954f  // 80^-0.5

typedef __bf16 bf16x8 __attribute__((ext_vector_type(8)));
typedef float  f32x4  __attribute__((ext_vector_type(4)));

__device__ __forceinline__ unsigned short f2b(float f) {   // f32 -> bf16 bits, RNE
    union { float f; unsigned int u; } v; v.f = f;
    unsigned int r = v.u + 0x7fffu + ((v.u >> 16) & 1u);
    return (unsigned short)(r >> 16);
}
__device__ __forceinline__ bf16x8 zero8() {
    bf16x8 z;
#pragma unroll
    for (int i = 0; i < 8; i++) z[i] = (__bf16)0.0f;
    return z;
}
__device__ __forceinline__ f32x4 zero4() {
    f32x4 z;
#pragma unroll
    for (int i = 0; i < 4; i++) z[i] = 0.0f;
    return z;
}

// ---------- f32 -> bf16 cast ----------
__global__ __launch_bounds__(256) void castk(const float* __restrict__ s,
                                             unsigned short* __restrict__ d, int n) {
    int i = (blockIdx.x * 256 + threadIdx.x) * 4;
    if (i < n) {
        float4 f = *(const float4*)(s + i);
        ushort4 o;
        o.x = f2b(f.x); o.y = f2b(f.y); o.z = f2b(f.z); o.w = f2b(f.w);
        *(ushort4*)(d + i) = o;
    }
}

// ---------- QKV projection, bf16 MFMA ----------
// z=0/1 -> q/k row-major bf16; z=2 -> v row-major f32. (verified GEMM pattern)
__global__ __launch_bounds__(256) void proj_qkv_mfma(
    const unsigned short* __restrict__ xb,
    const unsigned short* __restrict__ wqb,
    const unsigned short* __restrict__ wkb,
    const unsigned short* __restrict__ wvb,
    unsigned short* __restrict__ q16, unsigned short* __restrict__ k16,
    float* __restrict__ v32)
{
    __shared__ __align__(16) unsigned short Xs[64 * 72];
    __shared__ __align__(16) unsigned short Wsh[64 * 72];
    const int t = threadIdx.x;
    const int wvid = t >> 6, lane = t & 63, col = lane & 15, quad = lane >> 4;
    const int m0 = blockIdx.x * 64, i0 = blockIdx.y * 64, z = blockIdx.z;
    const unsigned short* W = (z == 0) ? wqb : (z == 1) ? wkb : wvb;
    const int row = t >> 2, seg = t & 3;

    f32x4 acc[4];
#pragma unroll
    for (int nt = 0; nt < 4; nt++) acc[nt] = zero4();

    for (int kt = 0; kt < INNER; kt += 64) {
        uint4 x0 = *(const uint4*)(xb + (size_t)(m0 + row) * INNER + kt + seg * 16);
        uint4 x1 = *(const uint4*)(xb + (size_t)(m0 + row) * INNER + kt + seg * 16 + 8);
        uint4 w0 = *(const uint4*)(W  + (size_t)(i0 + row) * INNER + kt + seg * 16);
        uint4 w1 = *(const uint4*)(W  + (size_t)(i0 + row) * INNER + kt + seg * 16 + 8);
        __syncthreads();
        *(uint4*)&Xs[row * 72 + seg * 16]      = x0;
        *(uint4*)&Xs[row * 72 + seg * 16 + 8]  = x1;
        *(uint4*)&Wsh[row * 72 + seg * 16]     = w0;
        *(uint4*)&Wsh[row * 72 + seg * 16 + 8] = w1;
        __syncthreads();
#pragma unroll
        for (int kbk = 0; kbk < 2; kbk++) {
            bf16x8 af = *(const bf16x8*)&Xs[(wvid * 16 + col) * 72 + kbk * 32 + quad * 8];
#pragma unroll
            for (int nt = 0; nt < 4; nt++) {
                bf16x8 bfr = *(const bf16x8*)&Wsh[(nt * 16 + col) * 72 + kbk * 32 + quad * 8];
                acc[nt] = __builtin_amdgcn_mfma_f32_16x16x32_bf16(af, bfr, acc[nt], 0, 0, 0);
            }
        }
    }
    if (z < 2) {
        unsigned short* Y = (z == 0) ? q16 : k16;
#pragma unroll
        for (int nt = 0; nt < 4; nt++)
#pragma unroll
            for (int r = 0; r < 4; r++)
                Y[(size_t)(m0 + wvid * 16 + quad * 4 + r) * INNER + i0 + nt * 16 + col] = f2b(acc[nt][r]);
    } else {
#pragma unroll
        for (int nt = 0; nt < 4; nt++)
#pragma unroll
            for (int r = 0; r < 4; r++)
                v32[(size_t)(m0 + wvid * 16 + quad * 4 + r) * INNER + i0 + nt * 16 + col] = acc[nt][r];
    }
}

// ---------- attention: MFMA QK^T + in-register softmax, f32 PV (round-3 verified) ----------
// 4 waves x 16 queries for S/softmax; P written f32 to Ss[64][65]; PV per-thread
// (row = t>>2 owns query row, c0 = (t&3)*20 owns 20-dim slice) exactly as round 3.
__global__ __launch_bounds__(256) void attn_qkmfma(
    const unsigned short* __restrict__ qb, const unsigned short* __restrict__ kb,
    const float* __restrict__ vb, const int* __restrict__ ctx,
    unsigned short* __restrict__ ao)
{
    __shared__ float Ss[64 * 65];
    __shared__ float Vs[64 * DHD];
    __shared__ float arow[64], lrow[64];

    const int t = threadIdx.x;
    const int wvid = t >> 6, lane = t & 63, col = lane & 15, quad = lane >> 4;
    const int qt = blockIdx.x, h = blockIdx.y, b = blockIdx.z;
    const int n0q = qt * 64;
    const int row = t >> 2;          // PV query row 0..63
    const int c0 = (t & 3) * 20;     // PV dim slice

    // Q fragments: wave's 16 queries, direct from global bf16 (A-layout m=col, k=quad*8+j)
    bf16x8 qf0, qf1, qf2;
    {
        const unsigned short* qp = qb + (size_t)(b * NNTOK + n0q + wvid * 16 + col) * INNER + h * DHD;
        qf0 = *(const bf16x8*)(qp + quad * 8);
        qf1 = *(const bf16x8*)(qp + 32 + quad * 8);
        qf2 = zero8();
        if (quad < 2) qf2 = *(const bf16x8*)(qp + 64 + quad * 8);
    }
    float m_r[4], l_r[4];
#pragma unroll
    for (int r = 0; r < 4; r++) { m_r[r] = -1e30f; l_r[r] = 0.0f; }
    float o[20];
#pragma unroll
    for (int i = 0; i < 20; i++) o[i] = 0.0f;

    for (int kc = 0; kc < (RRW * NNTOK) / 64; kc++) {   // 48 key chunks
        const int fr = ctx[b * RRW + (kc >> 4)];
        const int tok0 = (kc & 15) * 64;

        __syncthreads();   // previous PV reads of Ss/Vs/arow complete

        // S = Q K^T via MFMA, K frags direct from global bf16
        f32x4 s[4];
#pragma unroll
        for (int n0 = 0; n0 < 4; n0++) {
            const unsigned short* kp = kb + (size_t)(fr * NNTOK + tok0 + n0 * 16 + col) * INNER + h * DHD;
            bf16x8 k0 = *(const bf16x8*)(kp + quad * 8);
            bf16x8 k1 = *(const bf16x8*)(kp + 32 + quad * 8);
            bf16x8 k2 = zero8();
            if (quad < 2) k2 = *(const bf16x8*)(kp + 64 + quad * 8);
            f32x4 sv = zero4();
            sv = __builtin_amdgcn_mfma_f32_16x16x32_bf16(qf0, k0, sv, 0, 0, 0);
            sv = __builtin_amdgcn_mfma_f32_16x16x32_bf16(qf1, k1, sv, 0, 0, 0);
            sv = __builtin_amdgcn_mfma_f32_16x16x32_bf16(qf2, k2, sv, 0, 0, 0);
            s[n0] = sv;
        }
        // V chunk -> LDS, f32 natural [key][dim] (round-3 verified pattern)
        {
            const size_t vsrc = (size_t)(fr * NNTOK + tok0 + row) * INNER + h * DHD + c0;
#pragma unroll
            for (int v5 = 0; v5 < 5; v5++) {
                float4 f = *(const float4*)(vb + vsrc + v5 * 4);
                *(float4*)&Vs[row * DHD + c0 + v5 * 4] = f;
            }
        }
        // in-register online softmax over C-layout rows; P -> Ss (f32), alpha -> arow
#pragma unroll
        for (int r = 0; r < 4; r++) {
            const int qrow = wvid * 16 + quad * 4 + r;
            float s0 = s[0][r] * SCALE, s1 = s[1][r] * SCALE;
            float s2 = s[2][r] * SCALE, s3 = s[3][r] * SCALE;
            float v = fmaxf(fmaxf(s0, s1), fmaxf(s2, s3));
            v = fmaxf(v, __shfl_xor(v, 1));
            v = fmaxf(v, __shfl_xor(v, 2));
            v = fmaxf(v, __shfl_xor(v, 4));
            v = fmaxf(v, __shfl_xor(v, 8));
            float mnew = fmaxf(m_r[r], v);
            float al = __expf(m_r[r] - mnew);
            m_r[r] = mnew;
            float p0 = __expf(s0 - mnew), p1 = __expf(s1 - mnew);
            float p2 = __expf(s2 - mnew), p3 = __expf(s3 - mnew);
            float sum = p0 + p1 + p2 + p3;
            sum += __shfl_xor(sum, 1);
            sum += __shfl_xor(sum, 2);
            sum += __shfl_xor(sum, 4);
            sum += __shfl_xor(sum, 8);
            l_r[r] = l_r[r] * al + sum;
            Ss[qrow * 65 +      col] = p0;
            Ss[qrow * 65 + 16 + col] = p1;
            Ss[qrow * 65 + 32 + col] = p2;
            Ss[qrow * 65 + 48 + col] = p3;
            if (col == 0) arow[qrow] = al;
        }
        __syncthreads();   // P, arow, V visible to PV threads
        // PV, f32 (round-3 verified)
        {
            float al2 = arow[row];
#pragma unroll
            for (int i = 0; i < 20; i++) o[i] *= al2;
            for (int j = 0; j < 64; j++) {
                float p = Ss[row * 65 + j];
#pragma unroll
                for (int v5 = 0; v5 < 5; v5++) {
                    float4 vv = *(const float4*)&Vs[j * DHD + c0 + v5 * 4];
                    o[v5 * 4 + 0] += p * vv.x;
                    o[v5 * 4 + 1] += p * vv.y;
                    o[v5 * 4 + 2] += p * vv.z;
                    o[v5 * 4 + 3] += p * vv.w;
                }
            }
        }
    }
    // bridge per-wave l to PV threads
    if (col == 0) {
#pragma unroll
        for (int r = 0; r < 4; r++) lrow[wvid * 16 + quad * 4 + r] = l_r[r];
    }
    __syncthreads();
    const float inv = 1.0f / lrow[row];
    unsigned short* op = ao + (size_t)(b * NNTOK + n0q + row) * INNER + h * DHD + c0;
#pragma unroll
    for (int v5 = 0; v5 < 5; v5++) {
        op[v5 * 4 + 0] = f2b(o[v5 * 4 + 0] * inv);
        op[v5 * 4 + 1] = f2b(o[v5 * 4 + 1] * inv);
        op[v5 * 4 + 2] = f2b(o[v5 * 4 + 2] * inv);
        op[v5 * 4 + 3] = f2b(o[v5 * 4 + 3] * inv);
    }
}

// ---------- out projection, bf16 MFMA, f32 output + bias (verified) ----------
__global__ __launch_bounds__(256) void proj_out_mfma(
    const unsigned short* __restrict__ ab, const unsigned short* __restrict__ wob,
    const float* __restrict__ bo, float* __restrict__ out)
{
    __shared__ __align__(16) unsigned short Xs[64 * 72];
    __shared__ __align__(16) unsigned short Wsh[64 * 72];
    const int t = threadIdx.x;
    const int wvid = t >> 6, lane = t & 63, col = lane & 15, quad = lane >> 4;
    const int m0 = blockIdx.x * 64, i0 = blockIdx.y * 64;
    const int row = t >> 2, seg = t & 3;

    float bias[4];
#pragma unroll
    for (int nt = 0; nt < 4; nt++) bias[nt] = bo[i0 + nt * 16 + col];

    f32x4 acc[4];
#pragma unroll
    for (int nt = 0; nt < 4; nt++) acc[nt] = zero4();

    for (int kt = 0; kt < INNER; kt += 64) {
        uint4 x0 = *(const uint4*)(ab  + (size_t)(m0 + row) * INNER + kt + seg * 16);
        uint4 x1 = *(const uint4*)(ab  + (size_t)(m0 + row) * INNER + kt + seg * 16 + 8);
        uint4 w0 = *(const uint4*)(wob + (size_t)(i0 + row) * INNER + kt + seg * 16);
        uint4 w1 = *(const uint4*)(wob + (size_t)(i0 + row) * INNER + kt + seg * 16 + 8);
        __syncthreads();
        *(uint4*)&Xs[row * 72 + seg * 16]      = x0;
        *(uint4*)&Xs[row * 72 + seg * 16 + 8]  = x1;
        *(uint4*)&Wsh[row * 72 + seg * 16]     = w0;
        *(uint4*)&Wsh[row * 72 + seg * 16 + 8] = w1;
        __syncthreads();
#pragma unroll
        for (int kbk = 0; kbk < 2; kbk++) {
            bf16x8 af = *(const bf16x8*)&Xs[(wvid * 16 + col) * 72 + kbk * 32 + quad * 8];
#pragma unroll
            for (int nt = 0; nt < 4; nt++) {
                bf16x8 bfr = *(const bf16x8*)&Wsh[(nt * 16 + col) * 72 + kbk * 32 + quad * 8];
                acc[nt] = __builtin_amdgcn_mfma_f32_16x16x32_bf16(af, bfr, acc[nt], 0, 0, 0);
            }
        }
    }
#pragma unroll
    for (int nt = 0; nt < 4; nt++)
#pragma unroll
        for (int r = 0; r < 4; r++)
            out[(size_t)(m0 + wvid * 16 + quad * 4 + r) * CCH + i0 + nt * 16 + col] = acc[nt][r] + bias[nt];
}

extern "C" void kernel_launch(void* const* d_in, const int* in_sizes, int n_in,
                              void* d_out, int out_size, void* d_ws, size_t ws_size,
                              hipStream_t stream) {
    const float* x  = (const float*)d_in[0];
    const float* wq = (const float*)d_in[1];
    const float* wk = (const float*)d_in[2];
    const float* wv = (const float*)d_in[3];
    const float* wo = (const float*)d_in[4];
    const float* bo = (const float*)d_in[5];
    const int* ctx  = (const int*)d_in[6];
    float* out = (float*)d_out;

    const size_t XN = (size_t)MM * INNER;     // 5,242,880
    const size_t WN = (size_t)INNER * CCH;    //   409,600
    unsigned short* q16 = (unsigned short*)d_ws;            // bf16
    unsigned short* k16 = q16 + XN;                         // bf16
    float*          v32 = (float*)(k16 + XN);               // f32
    unsigned short* xb  = (unsigned short*)(v32 + XN);      // bf16 x (dead after proj)
    unsigned short* aob = xb;                               // alias: attn output bf16
    unsigned short* wqb = xb + XN;
    unsigned short* wkb = wqb + WN;
    unsigned short* wvb = wkb + WN;
    unsigned short* wob = wvb + WN;                         // total ~55.7 MB

    castk<<<dim3((XN / 4 + 255) / 256), 256, 0, stream>>>(x,  xb,  (int)XN);
    castk<<<dim3((WN / 4 + 255) / 256), 256, 0, stream>>>(wq, wqb, (int)WN);
    castk<<<dim3((WN / 4 + 255) / 256), 256, 0, stream>>>(wk, wkb, (int)WN);
    castk<<<dim3((WN / 4 + 255) / 256), 256, 0, stream>>>(wv, wvb, (int)WN);
    castk<<<dim3((WN / 4 + 255) / 256), 256, 0, stream>>>(wo, wob, (int)WN);

    proj_qkv_mfma<<<dim3(MM / 64, INNER / 64, 3), 256, 0, stream>>>(xb, wqb, wkb, wvb, q16, k16, v32);
    attn_qkmfma<<<dim3(NNTOK / 64, HH, BB), 256, 0, stream>>>(q16, k16, v32, ctx, aob);
    proj_out_mfma<<<dim3(MM / 64, CCH / 64), 256, 0, stream>>>(aob, wob, bo, out);
}

// Round 8
// 432.624 us; speedup vs baseline: 3.5726x; 2.0451x over previous
//
#include <hip/hip_runtime.h>
#include <hip/hip_bf16.h>

#define BB    8
#define NNTOK 1024
#define CCH   640
#define HH    8
#define DHD   80
#define RRW   3
#define MM    (BB * NNTOK)      // 8192
#define INNER 640
#define SCALE 0.111803398874989484820458954f  // 80^-0.5

typedef __bf16 bf16x8 __attribute__((ext_vector_type(8)));
typedef float  f32x4  __attribute__((ext_vector_type(4)));

__device__ __forceinline__ unsigned short f2b(float f) {   // f32 -> bf16 bits, RNE
    union { float f; unsigned int u; } v; v.f = f;
    unsigned int r = v.u + 0x7fffu + ((v.u >> 16) & 1u);
    return (unsigned short)(r >> 16);
}
__device__ __forceinline__ float b2f(unsigned short u) {
    union { unsigned int u; float f; } v; v.u = ((unsigned int)u) << 16; return v.f;
}
__device__ __forceinline__ bf16x8 zero8() {
    bf16x8 z;
#pragma unroll
    for (int i = 0; i < 8; i++) z[i] = (__bf16)0.0f;
    return z;
}
__device__ __forceinline__ f32x4 zero4() {
    f32x4 z;
#pragma unroll
    for (int i = 0; i < 4; i++) z[i] = 0.0f;
    return z;
}

// ---------- f32 -> bf16 cast ----------
__global__ __launch_bounds__(256) void castk(const float* __restrict__ s,
                                             unsigned short* __restrict__ d, int n) {
    int i = (blockIdx.x * 256 + threadIdx.x) * 4;
    if (i < n) {
        float4 f = *(const float4*)(s + i);
        ushort4 o;
        o.x = f2b(f.x); o.y = f2b(f.y); o.z = f2b(f.z); o.w = f2b(f.w);
        *(ushort4*)(d + i) = o;
    }
}

// ---------- QKV projection, bf16 MFMA (verified) ----------
// z=0/1 -> q/k row-major bf16; z=2 -> v row-major f32.
__global__ __launch_bounds__(256) void proj_qkv_mfma(
    const unsigned short* __restrict__ xb,
    const unsigned short* __restrict__ wqb,
    const unsigned short* __restrict__ wkb,
    const unsigned short* __restrict__ wvb,
    unsigned short* __restrict__ q16, unsigned short* __restrict__ k16,
    float* __restrict__ v32)
{
    __shared__ __align__(16) unsigned short Xs[64 * 72];
    __shared__ __align__(16) unsigned short Wsh[64 * 72];
    const int t = threadIdx.x;
    const int wvid = t >> 6, lane = t & 63, col = lane & 15, quad = lane >> 4;
    const int m0 = blockIdx.x * 64, i0 = blockIdx.y * 64, z = blockIdx.z;
    const unsigned short* W = (z == 0) ? wqb : (z == 1) ? wkb : wvb;
    const int row = t >> 2, seg = t & 3;

    f32x4 acc[4];
#pragma unroll
    for (int nt = 0; nt < 4; nt++) acc[nt] = zero4();

    for (int kt = 0; kt < INNER; kt += 64) {
        uint4 x0 = *(const uint4*)(xb + (size_t)(m0 + row) * INNER + kt + seg * 16);
        uint4 x1 = *(const uint4*)(xb + (size_t)(m0 + row) * INNER + kt + seg * 16 + 8);
        uint4 w0 = *(const uint4*)(W  + (size_t)(i0 + row) * INNER + kt + seg * 16);
        uint4 w1 = *(const uint4*)(W  + (size_t)(i0 + row) * INNER + kt + seg * 16 + 8);
        __syncthreads();
        *(uint4*)&Xs[row * 72 + seg * 16]      = x0;
        *(uint4*)&Xs[row * 72 + seg * 16 + 8]  = x1;
        *(uint4*)&Wsh[row * 72 + seg * 16]     = w0;
        *(uint4*)&Wsh[row * 72 + seg * 16 + 8] = w1;
        __syncthreads();
#pragma unroll
        for (int kbk = 0; kbk < 2; kbk++) {
            bf16x8 af = *(const bf16x8*)&Xs[(wvid * 16 + col) * 72 + kbk * 32 + quad * 8];
#pragma unroll
            for (int nt = 0; nt < 4; nt++) {
                bf16x8 bfr = *(const bf16x8*)&Wsh[(nt * 16 + col) * 72 + kbk * 32 + quad * 8];
                acc[nt] = __builtin_amdgcn_mfma_f32_16x16x32_bf16(af, bfr, acc[nt], 0, 0, 0);
            }
        }
    }
    if (z < 2) {
        unsigned short* Y = (z == 0) ? q16 : k16;
#pragma unroll
        for (int nt = 0; nt < 4; nt++)
#pragma unroll
            for (int r = 0; r < 4; r++)
                Y[(size_t)(m0 + wvid * 16 + quad * 4 + r) * INNER + i0 + nt * 16 + col] = f2b(acc[nt][r]);
    } else {
#pragma unroll
        for (int nt = 0; nt < 4; nt++)
#pragma unroll
            for (int r = 0; r < 4; r++)
                v32[(size_t)(m0 + wvid * 16 + quad * 4 + r) * INNER + i0 + nt * 16 + col] = acc[nt][r];
    }
}

// ---------- attention: MFMA QK^T (verified) + MFMA PV via P bf16 LDS round-trip ----------
// 4 waves x 16 queries. P: C-layout regs -> bf16 -> per-wave LDS strip (stride 72)
// -> A-frag b128 reads (same read shape as verified proj af reads).
// V: f32 global row-major -> bf16 transposed LDS Vt[dim][key] (stride 72) -> B-frags.
__global__ __launch_bounds__(256) void attn_mfma2(
    const unsigned short* __restrict__ qb, const unsigned short* __restrict__ kb,
    const float* __restrict__ vb, const int* __restrict__ ctx,
    unsigned short* __restrict__ ao)
{
    __shared__ __align__(16) unsigned short Pl[4][16 * 72];
    __shared__ __align__(16) unsigned short Vt[80 * 72];
    const int t = threadIdx.x;
    const int wvid = t >> 6, lane = t & 63, col = lane & 15, quad = lane >> 4;
    const int qt = blockIdx.x, h = blockIdx.y, b = blockIdx.z;
    const int row = t >> 2;        // staging: key index 0..63
    const int c0 = (t & 3) * 20;   // staging: dim slice

    // Q fragments (A-layout m=col, k=quad*8+j), direct from global bf16 [verified r7]
    bf16x8 qf0, qf1, qf2;
    {
        const unsigned short* qp = qb + (size_t)(b * NNTOK + qt * 64 + wvid * 16 + col) * INNER + h * DHD;
        qf0 = *(const bf16x8*)(qp + quad * 8);
        qf1 = *(const bf16x8*)(qp + 32 + quad * 8);
        qf2 = zero8();
        if (quad < 2) qf2 = *(const bf16x8*)(qp + 64 + quad * 8);
    }
    f32x4 o[5];
#pragma unroll
    for (int dt = 0; dt < 5; dt++) o[dt] = zero4();
    float m_r[4], l_r[4];
#pragma unroll
    for (int r = 0; r < 4; r++) { m_r[r] = -1e30f; l_r[r] = 0.0f; }
    unsigned short* pw = &Pl[wvid][0];

    for (int kc = 0; kc < (RRW * NNTOK) / 64; kc++) {   // 48 key chunks
        const int fr = ctx[b * RRW + (kc >> 4)];
        const int tok0 = (kc & 15) * 64;

        __syncthreads();   // WAR: previous chunk's Vt/Pl frag reads complete

        // stage V chunk: f32 global [key][dim] -> bf16 LDS Vt[dim][key]
        {
            const float* vsrc = vb + (size_t)(fr * NNTOK + tok0 + row) * INNER + h * DHD + c0;
#pragma unroll
            for (int v5 = 0; v5 < 5; v5++) {
                float4 f = *(const float4*)(vsrc + v5 * 4);
                Vt[(c0 + v5 * 4 + 0) * 72 + row] = f2b(f.x);
                Vt[(c0 + v5 * 4 + 1) * 72 + row] = f2b(f.y);
                Vt[(c0 + v5 * 4 + 2) * 72 + row] = f2b(f.z);
                Vt[(c0 + v5 * 4 + 3) * 72 + row] = f2b(f.w);
            }
        }
        // S = Q K^T via MFMA, K frags direct from global bf16 [verified r7]
        f32x4 s[4];
#pragma unroll
        for (int n0 = 0; n0 < 4; n0++) {
            const unsigned short* kp = kb + (size_t)(fr * NNTOK + tok0 + n0 * 16 + col) * INNER + h * DHD;
            bf16x8 k0 = *(const bf16x8*)(kp + quad * 8);
            bf16x8 k1 = *(const bf16x8*)(kp + 32 + quad * 8);
            bf16x8 k2 = zero8();
            if (quad < 2) k2 = *(const bf16x8*)(kp + 64 + quad * 8);
            f32x4 sv = zero4();
            sv = __builtin_amdgcn_mfma_f32_16x16x32_bf16(qf0, k0, sv, 0, 0, 0);
            sv = __builtin_amdgcn_mfma_f32_16x16x32_bf16(qf1, k1, sv, 0, 0, 0);
            sv = __builtin_amdgcn_mfma_f32_16x16x32_bf16(qf2, k2, sv, 0, 0, 0);
            s[n0] = sv;
        }
        // in-register online softmax [verified r7]; P -> bf16 -> per-wave strip
#pragma unroll
        for (int r = 0; r < 4; r++) {
            float s0 = s[0][r] * SCALE, s1 = s[1][r] * SCALE;
            float s2 = s[2][r] * SCALE, s3 = s[3][r] * SCALE;
            float v = fmaxf(fmaxf(s0, s1), fmaxf(s2, s3));
            v = fmaxf(v, __shfl_xor(v, 1));
            v = fmaxf(v, __shfl_xor(v, 2));
            v = fmaxf(v, __shfl_xor(v, 4));
            v = fmaxf(v, __shfl_xor(v, 8));
            float mnew = fmaxf(m_r[r], v);
            float al = __expf(m_r[r] - mnew);
            m_r[r] = mnew;
            float p0 = __expf(s0 - mnew), p1 = __expf(s1 - mnew);
            float p2 = __expf(s2 - mnew), p3 = __expf(s3 - mnew);
            unsigned short pb0 = f2b(p0), pb1 = f2b(p1), pb2 = f2b(p2), pb3 = f2b(p3);
            float sum = b2f(pb0) + b2f(pb1) + b2f(pb2) + b2f(pb3);  // consistent with bf16 P
            sum += __shfl_xor(sum, 1);
            sum += __shfl_xor(sum, 2);
            sum += __shfl_xor(sum, 4);
            sum += __shfl_xor(sum, 8);
            l_r[r] = l_r[r] * al + sum;
#pragma unroll
            for (int dt = 0; dt < 5; dt++) o[dt][r] *= al;
            const int rowoff = (quad * 4 + r) * 72;
            pw[rowoff +      col] = pb0;
            pw[rowoff + 16 + col] = pb1;
            pw[rowoff + 32 + col] = pb2;
            pw[rowoff + 48 + col] = pb3;
        }
        __syncthreads();   // RAW: Vt (cross-wave) and Pl stores ordered before frag reads

        bf16x8 pa0 = *(const bf16x8*)(pw + col * 72 + quad * 8);
        bf16x8 pa1 = *(const bf16x8*)(pw + col * 72 + 32 + quad * 8);
#pragma unroll
        for (int dt = 0; dt < 5; dt++) {
            bf16x8 v0 = *(const bf16x8*)&Vt[(dt * 16 + col) * 72 + quad * 8];
            bf16x8 v1 = *(const bf16x8*)&Vt[(dt * 16 + col) * 72 + 32 + quad * 8];
            o[dt] = __builtin_amdgcn_mfma_f32_16x16x32_bf16(pa0, v0, o[dt], 0, 0, 0);
            o[dt] = __builtin_amdgcn_mfma_f32_16x16x32_bf16(pa1, v1, o[dt], 0, 0, 0);
        }
    }
    // epilogue: C-layout store (row=quad*4+r -> query, col -> dim within 16-tile)
#pragma unroll
    for (int r = 0; r < 4; r++) {
        const float inv = 1.0f / l_r[r];
        unsigned short* op = ao + (size_t)(b * NNTOK + qt * 64 + wvid * 16 + quad * 4 + r) * INNER + h * DHD;
#pragma unroll
        for (int dt = 0; dt < 5; dt++)
            op[dt * 16 + col] = f2b(o[dt][r] * inv);
    }
}

// ---------- out projection, bf16 MFMA, f32 output + bias (verified) ----------
__global__ __launch_bounds__(256) void proj_out_mfma(
    const unsigned short* __restrict__ ab, const unsigned short* __restrict__ wob,
    const float* __restrict__ bo, float* __restrict__ out)
{
    __shared__ __align__(16) unsigned short Xs[64 * 72];
    __shared__ __align__(16) unsigned short Wsh[64 * 72];
    const int t = threadIdx.x;
    const int wvid = t >> 6, lane = t & 63, col = lane & 15, quad = lane >> 4;
    const int m0 = blockIdx.x * 64, i0 = blockIdx.y * 64;
    const int row = t >> 2, seg = t & 3;

    float bias[4];
#pragma unroll
    for (int nt = 0; nt < 4; nt++) bias[nt] = bo[i0 + nt * 16 + col];

    f32x4 acc[4];
#pragma unroll
    for (int nt = 0; nt < 4; nt++) acc[nt] = zero4();

    for (int kt = 0; kt < INNER; kt += 64) {
        uint4 x0 = *(const uint4*)(ab  + (size_t)(m0 + row) * INNER + kt + seg * 16);
        uint4 x1 = *(const uint4*)(ab  + (size_t)(m0 + row) * INNER + kt + seg * 16 + 8);
        uint4 w0 = *(const uint4*)(wob + (size_t)(i0 + row) * INNER + kt + seg * 16);
        uint4 w1 = *(const uint4*)(wob + (size_t)(i0 + row) * INNER + kt + seg * 16 + 8);
        __syncthreads();
        *(uint4*)&Xs[row * 72 + seg * 16]      = x0;
        *(uint4*)&Xs[row * 72 + seg * 16 + 8]  = x1;
        *(uint4*)&Wsh[row * 72 + seg * 16]     = w0;
        *(uint4*)&Wsh[row * 72 + seg * 16 + 8] = w1;
        __syncthreads();
#pragma unroll
        for (int kbk = 0; kbk < 2; kbk++) {
            bf16x8 af = *(const bf16x8*)&Xs[(wvid * 16 + col) * 72 + kbk * 32 + quad * 8];
#pragma unroll
            for (int nt = 0; nt < 4; nt++) {
                bf16x8 bfr = *(const bf16x8*)&Wsh[(nt * 16 + col) * 72 + kbk * 32 + quad * 8];
                acc[nt] = __builtin_amdgcn_mfma_f32_16x16x32_bf16(af, bfr, acc[nt], 0, 0, 0);
            }
        }
    }
#pragma unroll
    for (int nt = 0; nt < 4; nt++)
#pragma unroll
        for (int r = 0; r < 4; r++)
            out[(size_t)(m0 + wvid * 16 + quad * 4 + r) * CCH + i0 + nt * 16 + col] = acc[nt][r] + bias[nt];
}

extern "C" void kernel_launch(void* const* d_in, const int* in_sizes, int n_in,
                              void* d_out, int out_size, void* d_ws, size_t ws_size,
                              hipStream_t stream) {
    const float* x  = (const float*)d_in[0];
    const float* wq = (const float*)d_in[1];
    const float* wk = (const float*)d_in[2];
    const float* wv = (const float*)d_in[3];
    const float* wo = (const float*)d_in[4];
    const float* bo = (const float*)d_in[5];
    const int* ctx  = (const int*)d_in[6];
    float* out = (float*)d_out;

    const size_t XN = (size_t)MM * INNER;     // 5,242,880
    const size_t WN = (size_t)INNER * CCH;    //   409,600
    unsigned short* q16 = (unsigned short*)d_ws;            // bf16
    unsigned short* k16 = q16 + XN;                         // bf16
    float*          v32 = (float*)(k16 + XN);               // f32
    unsigned short* xb  = (unsigned short*)(v32 + XN);      // bf16 x (dead after proj)
    unsigned short* aob = xb;                               // alias: attn output bf16
    unsigned short* wqb = xb + XN;
    unsigned short* wkb = wqb + WN;
    unsigned short* wvb = wkb + WN;
    unsigned short* wob = wvb + WN;                         // total ~55.7 MB

    castk<<<dim3((XN / 4 + 255) / 256), 256, 0, stream>>>(x,  xb,  (int)XN);
    castk<<<dim3((WN / 4 + 255) / 256), 256, 0, stream>>>(wq, wqb, (int)WN);
    castk<<<dim3((WN / 4 + 255) / 256), 256, 0, stream>>>(wk, wkb, (int)WN);
    castk<<<dim3((WN / 4 + 255) / 256), 256, 0, stream>>>(wv, wvb, (int)WN);
    castk<<<dim3((WN / 4 + 255) / 256), 256, 0, stream>>>(wo, wob, (int)WN);

    proj_qkv_mfma<<<dim3(MM / 64, INNER / 64, 3), 256, 0, stream>>>(xb, wqb, wkb, wvb, q16, k16, v32);
    attn_mfma2<<<dim3(NNTOK / 64, HH, BB), 256, 0, stream>>>(q16, k16, v32, ctx, aob);
    proj_out_mfma<<<dim3(MM / 64, CCH / 64), 256, 0, stream>>>(aob, wob, bo, out);
}